// Round 11
// baseline (363.136 us; speedup 1.0000x reference)
//
#include <hip/hip_runtime.h>
#include <hip/hip_bf16.h>
#include <cfloat>
#include <math.h>

// Problem constants
#define S_LEN 1024
#define DIM 512
#define H_N 8
#define DH 64
#define CB 32
#define NB 32
#define NSEL 4
#define NMEM 4
#define WIN 64
#define SCALE 0.125f
#define EPS 1.1920929e-07f

// ---------------- ws layout (float offsets) ----------------
#define OFF_X      0u          // 524288 (dead after qkv GEMM)
#define OFF_QKV    524288u     // 1024*1536
#define OFF_RQ     2097152u    // 524288
#define OFF_RK     2621440u    // 524288 (live through attn)
#define OFF_VBUF   3145728u    // 524288  v as [h][s][64]
#define OFF_CKC    3670016u    // 16384 (8*32*64)
#define OFF_CVC    3702784u    // 16384
#define OFF_STRAT  3735552u    // 24576
#define OFF_ATT    3760128u    // 524288
#define OFF_HK     4284416u    // 2*524288 (hk then hv contiguous)
#define OFF_QKVP   5332992u    // 2*1572864
#define OFF_COMPP  5332992u    // 8*524288 (after qkvp dead)
#define OFF_OUTP   5332992u    // 4*524288 (after compp dead)

// ---------------- RMSNorm + strategy gates (fused) ----------------
__global__ void rmsnorm_strat_k(const float* __restrict__ inp, const float* __restrict__ g,
                                const float* __restrict__ sw, const float* __restrict__ sb,
                                float* __restrict__ x, float* __restrict__ strat) {
    int s = blockIdx.x;
    int t = threadIdx.x;
    __shared__ __align__(16) float xs[512];
    __shared__ float red[24][8];
    float v0 = inp[s * DIM + t];
    float v1 = inp[s * DIM + t + 256];
    float ss = v0 * v0 + v1 * v1;
    for (int o = 32; o > 0; o >>= 1) ss += __shfl_xor(ss, o);
    __shared__ float wsum[4];
    int wid = t >> 6, lane = t & 63;
    if (lane == 0) wsum[wid] = ss;
    __syncthreads();
    float tot = wsum[0] + wsum[1] + wsum[2] + wsum[3];
    float scale = 1.0f / sqrtf(tot / (float)DIM + EPS);
    float x0 = v0 * scale * g[t];
    float x1 = v1 * scale * g[t + 256];
    x[s * DIM + t]       = x0;
    x[s * DIM + t + 256] = x1;
    xs[t] = x0;
    xs[t + 256] = x1;
    __syncthreads();
    if (t < 192) {
        int o = t >> 3, p = t & 7;
        float acc = 0.0f;
        const float* xb = xs + p * 64;
        for (int k = 0; k < 64; ++k) acc += xb[k] * sw[(p * 64 + k) * 24 + o];
        red[o][p] = acc;
    }
    __syncthreads();
    if (t < 24) {
        float a = sb[t];
        for (int p = 0; p < 8; ++p) a += red[t][p];
        strat[s * 24 + t] = 1.0f / (1.0f + expf(-a));
    }
}

// ---------------- f32 GEMM 64x64 tile, split-K partial writer (generic) ----------------
__device__ __forceinline__ void gemm_sk_body(const float* __restrict__ A, const float* __restrict__ B,
                                             float* __restrict__ P, int M, int N, int K,
                                             int kstart, int Ks) {
    __shared__ __align__(16) float As[2][16][68];
    __shared__ __align__(16) float Bs[2][16][64];
    const int bm = blockIdx.x * 64, bn = blockIdx.y * 64;
    const int tid = threadIdx.x;
    const int tx = tid & 15, ty = tid >> 4;
    const int ar = tid >> 2;
    const int ac = (tid & 3) * 4;
    const int br = tid >> 4;
    const int bc = (tid & 15) * 4;
    const float* Aptr = A + (size_t)(bm + ar) * K + kstart + ac;
    const float* Bptr = B + (size_t)(kstart + br) * N + bn + bc;

    float4 a4 = *(const float4*)(Aptr);
    float4 b4 = *(const float4*)(Bptr);
    float acc[4][4] = {};
    int buf = 0;
    for (int k0 = 0; k0 < Ks; k0 += 16) {
        As[buf][ac + 0][ar] = a4.x;
        As[buf][ac + 1][ar] = a4.y;
        As[buf][ac + 2][ar] = a4.z;
        As[buf][ac + 3][ar] = a4.w;
        *(float4*)&Bs[buf][br][bc] = b4;
        __syncthreads();
        if (k0 + 16 < Ks) {
            a4 = *(const float4*)(Aptr + k0 + 16);
            b4 = *(const float4*)(Bptr + (size_t)(k0 + 16) * N);
        }
#pragma unroll
        for (int kk = 0; kk < 16; ++kk) {
            const float4 af = *(const float4*)&As[buf][kk][ty * 4];
            const float4 bf = *(const float4*)&Bs[buf][kk][tx * 4];
            acc[0][0] += af.x * bf.x; acc[0][1] += af.x * bf.y; acc[0][2] += af.x * bf.z; acc[0][3] += af.x * bf.w;
            acc[1][0] += af.y * bf.x; acc[1][1] += af.y * bf.y; acc[1][2] += af.y * bf.z; acc[1][3] += af.y * bf.w;
            acc[2][0] += af.z * bf.x; acc[2][1] += af.z * bf.y; acc[2][2] += af.z * bf.z; acc[2][3] += af.z * bf.w;
            acc[3][0] += af.w * bf.x; acc[3][1] += af.w * bf.y; acc[3][2] += af.w * bf.z; acc[3][3] += af.w * bf.w;
        }
        buf ^= 1;
    }
#pragma unroll
    for (int i = 0; i < 4; ++i) {
        int m = bm + ty * 4 + i;
        float4 v;
        v.x = acc[i][0]; v.y = acc[i][1]; v.z = acc[i][2]; v.w = acc[i][3];
        *(float4*)&P[(size_t)m * N + bn + tx * 4] = v;
    }
}

__global__ void gemm_sk_k(const float* __restrict__ A, const float* __restrict__ B,
                          float* __restrict__ P, int M, int N, int K, int nsplit) {
    int kz = blockIdx.z;
    int Ks = K / nsplit;
    gemm_sk_body(A, B, P + (size_t)kz * M * N, M, N, K, kz * Ks, Ks);
}

// ---------------- qkv split-K reduce + emit vbuf [h][s][64] ----------------
__global__ void reduce_qkv_k(const float* __restrict__ P, float* __restrict__ qkv,
                             float* __restrict__ vbuf) {
    int idx4 = blockIdx.x * 256 + threadIdx.x;   // 393216 float4s
    const int mn4 = 393216;
    float4 v = ((const float4*)P)[idx4];
    float4 w = ((const float4*)P)[idx4 + mn4];
    v.x += w.x; v.y += w.y; v.z += w.z; v.w += w.w;
    ((float4*)qkv)[idx4] = v;
    int c = (idx4 % 384) * 4;      // col in [0,1536)  (384 not pow2 -> must use %, not &)
    if (c >= 1024) {
        int s = idx4 / 384;
        int h = (c - 1024) >> 6, d = (c - 1024) & 63;
        *(float4*)(vbuf + (size_t)h * 65536 + s * 64 + d) = v;
    }
}

// ---------------- RoPE apply (inline double-precision trig) ----------------
__global__ void rope_apply_k(const float* __restrict__ qkv,
                             float* __restrict__ rq, float* __restrict__ rk) {
    int idx = blockIdx.x * 256 + threadIdx.x;   // 1024*8*32 pairs
    int s = idx >> 8;
    int rem = idx & 255;
    int h = rem >> 5, i = rem & 31;
    double inv = pow(10000.0, -(double)i / 32.0);
    double ang = (double)s * inv;
    float c = (float)cos(ang), sn = (float)sin(ang);
    int qb = s * 1536 + h * 64 + 2 * i;
    float q0 = qkv[qb], q1 = qkv[qb + 1];
    int ob = s * 512 + h * 64 + 2 * i;
    rq[ob]     = q0 * c - q1 * sn;
    rq[ob + 1] = q1 * c + q0 * sn;
    float k0 = qkv[qb + 512], k1 = qkv[qb + 513];
    rk[ob]     = k0 * c - k1 * sn;
    rk[ob + 1] = k1 * c + k0 * sn;
}

// ---------------- comp-MLP layer1 GEMM with fused input build ----------------
__global__ void gemm_comp_k(const float* __restrict__ qkv, const float* __restrict__ k_pos,
                            const float* __restrict__ v_pos, const float* __restrict__ kw1,
                            const float* __restrict__ vw1, float* __restrict__ P) {
    int z = blockIdx.z, g = z >> 2, kz = z & 3;
    const float* B = g ? vw1 : kw1;
    const float* pos = g ? v_pos : k_pos;
    const int qoff = g ? 1024 : 512;
    const int kstart = kz * 512;
    __shared__ __align__(16) float As[2][16][68];
    __shared__ __align__(16) float Bs[2][16][64];
    const int bm = blockIdx.x * 64, bn = blockIdx.y * 64;
    const int tid = threadIdx.x;
    const int tx = tid & 15, ty = tid >> 4;
    const int ar = tid >> 2, ac = (tid & 3) * 4;
    const int br = tid >> 4, bc = (tid & 15) * 4;
    const int m = bm + ar;
    const int hh = m >> 5, nb = m & 31;
    const float* qb = qkv + (size_t)(nb * 32) * 1536 + qoff + hh * 64;
    const float* pb = pos + hh * 2048;
    const float* Bptr = B + (size_t)(kstart + br) * 2048 + bn + bc;

    auto loadA = [&](int kk) {
        int cb = kk >> 6, d = kk & 63;
        float4 a = *(const float4*)(qb + (size_t)cb * 1536 + d);
        float4 p = *(const float4*)(pb + cb * 64 + d);
        a.x += p.x; a.y += p.y; a.z += p.z; a.w += p.w;
        return a;
    };

    float4 a4 = loadA(kstart + ac);
    float4 b4 = *(const float4*)Bptr;
    float acc[4][4] = {};
    int buf = 0;
    for (int k0 = 0; k0 < 512; k0 += 16) {
        As[buf][ac + 0][ar] = a4.x;
        As[buf][ac + 1][ar] = a4.y;
        As[buf][ac + 2][ar] = a4.z;
        As[buf][ac + 3][ar] = a4.w;
        *(float4*)&Bs[buf][br][bc] = b4;
        __syncthreads();
        if (k0 + 16 < 512) {
            a4 = loadA(kstart + ac + k0 + 16);
            b4 = *(const float4*)(Bptr + (size_t)(k0 + 16) * 2048);
        }
#pragma unroll
        for (int kk = 0; kk < 16; ++kk) {
            const float4 af = *(const float4*)&As[buf][kk][ty * 4];
            const float4 bf = *(const float4*)&Bs[buf][kk][tx * 4];
            acc[0][0] += af.x * bf.x; acc[0][1] += af.x * bf.y; acc[0][2] += af.x * bf.z; acc[0][3] += af.x * bf.w;
            acc[1][0] += af.y * bf.x; acc[1][1] += af.y * bf.y; acc[1][2] += af.y * bf.z; acc[1][3] += af.y * bf.w;
            acc[2][0] += af.z * bf.x; acc[2][1] += af.z * bf.y; acc[2][2] += af.z * bf.z; acc[2][3] += af.z * bf.w;
            acc[3][0] += af.w * bf.x; acc[3][1] += af.w * bf.y; acc[3][2] += af.w * bf.z; acc[3][3] += af.w * bf.w;
        }
        buf ^= 1;
    }
    float* Pz = P + (size_t)z * 524288;
#pragma unroll
    for (int i = 0; i < 4; ++i) {
        int mm = bm + ty * 4 + i;
        float4 v;
        v.x = acc[i][0]; v.y = acc[i][1]; v.z = acc[i][2]; v.w = acc[i][3];
        *(float4*)&Pz[(size_t)mm * 2048 + bn + tx * 4] = v;
    }
}

// ---------------- combined comp reduce: hk and hv (+bias,+relu) ----------------
__global__ void reduce_comp_k(const float* __restrict__ P, const float* __restrict__ kb,
                              const float* __restrict__ vb, float* __restrict__ hkv) {
    int idx4 = blockIdx.x * 256 + threadIdx.x;   // 262144 float4s total
    const int half4 = 131072;                     // per matrix
    int which = idx4 >= half4 ? 1 : 0;
    int l4 = idx4 - which * half4;
    const float4* p4 = (const float4*)P + (size_t)which * 4 * half4 + l4;
    float4 v = p4[0];
    float4 w1 = p4[half4], w2 = p4[2 * half4], w3 = p4[3 * (size_t)half4];
    v.x += w1.x + w2.x + w3.x; v.y += w1.y + w2.y + w3.y;
    v.z += w1.z + w2.z + w3.z; v.w += w1.w + w2.w + w3.w;
    int col = (l4 * 4) & 2047;
    const float* bias = (which ? vb : kb) + col;
    v.x = fmaxf(v.x + bias[0], 0.f); v.y = fmaxf(v.y + bias[1], 0.f);
    v.z = fmaxf(v.z + bias[2], 0.f); v.w = fmaxf(v.w + bias[3], 0.f);
    *(float4*)(hkv + (size_t)which * 524288 + (size_t)l4 * 4) = v;
}

// ---------------- generic split-K reduce (out proj) ----------------
template <int NS>
__global__ void reduce_k(const float* __restrict__ P, float* __restrict__ Y, int MN) {
    int idx4 = blockIdx.x * 256 + threadIdx.x;
    if (idx4 * 4 >= MN) return;
    const float4* p4 = (const float4*)P;
    int mn4 = MN >> 2;
    float4 v = p4[idx4];
#pragma unroll
    for (int j = 1; j < NS; ++j) {
        float4 w = p4[idx4 + (size_t)j * mn4];
        v.x += w.x; v.y += w.y; v.z += w.z; v.w += w.w;
    }
    ((float4*)Y)[idx4] = v;
}

// ---------------- skinny GEMM: layer2 -> ckc / cvc (both row-major) ----------------
__global__ void gemm_skinny_z2_k(const float* __restrict__ hkv, const float* __restrict__ kw2,
                                 const float* __restrict__ kb2, const float* __restrict__ vw2,
                                 const float* __restrict__ vb2, float* __restrict__ ckc,
                                 float* __restrict__ cvc) {
    int z = blockIdx.z;
    const float* A = hkv + (size_t)z * 524288;
    const float* B = z ? vw2 : kw2;
    const float* bias = z ? vb2 : kb2;
    int row = blockIdx.x;
    int col = threadIdx.x & 63;
    int chunk = threadIdx.x >> 6;
    const float* a = A + (size_t)row * 2048 + chunk * 512;
    const float* b = B + (size_t)chunk * 512 * 64;
    float acc = 0.0f;
    for (int k = 0; k < 512; k += 4) {
        float4 av = *(const float4*)(a + k);
        acc += av.x * b[(k + 0) * 64 + col];
        acc += av.y * b[(k + 1) * 64 + col];
        acc += av.z * b[(k + 2) * 64 + col];
        acc += av.w * b[(k + 3) * 64 + col];
    }
    __shared__ float red[4][64];
    red[chunk][col] = acc;
    __syncthreads();
    if (chunk == 0) {
        float v = red[0][col] + red[1][col] + red[2][col] + red[3][col] + bias[col];
        if (z == 0) ckc[(size_t)row * 64 + col] = v;
        else        cvc[(size_t)row * 64 + col] = v;
    }
}

// ---------------- helpers ----------------
__device__ __forceinline__ float redmax64(float v) {
    for (int o = 32; o > 0; o >>= 1) v = fmaxf(v, __shfl_xor(v, o));
    return v;
}
__device__ __forceinline__ float redsum64(float v) {
    for (int o = 32; o > 0; o >>= 1) v += __shfl_xor(v, o);
    return v;
}
// 4-accumulator dot: q from wave-local LDS (broadcast reads), per-lane k row float4s
__device__ __forceinline__ float dot64i(const float* __restrict__ qsh, const float* __restrict__ kr) {
    const float4* q4 = (const float4*)qsh;
    const float4* k4 = (const float4*)kr;
    float a0 = 0, a1 = 0, a2 = 0, a3 = 0;
#pragma unroll
    for (int i = 0; i < 16; i += 4) {
        float4 qa = q4[i],     ka = k4[i];
        float4 qb = q4[i + 1], kb = k4[i + 1];
        float4 qc = q4[i + 2], kc = k4[i + 2];
        float4 qd = q4[i + 3], kd = k4[i + 3];
        a0 += (qa.x * ka.x + qa.y * ka.y) + (qa.z * ka.z + qa.w * ka.w);
        a1 += (qb.x * kb.x + qb.y * kb.y) + (qb.z * kb.z + qb.w * kb.w);
        a2 += (qc.x * kc.x + qc.y * kc.y) + (qc.z * kc.z + qc.w * kc.w);
        a3 += (qd.x * kd.x + qd.y * kd.y) + (qd.z * kd.z + qd.w * kd.w);
    }
    return (a0 + a1) + (a2 + a3);
}

// ---------------- fused attention: 4 independent waves / block, per-wave LDS, NO barriers ----------------
// wave w -> s = blockIdx.x*4 + w, head = blockIdx.y. All LDS use is wave-local
// (write->read within the same wave needs only compiler-inserted lgkmcnt, no s_barrier).
__global__ __launch_bounds__(256) void attn_fused_k(
    const float* __restrict__ qkv, const float* __restrict__ rq,
    const float* __restrict__ rk, const float* __restrict__ ckc,
    const float* __restrict__ cvc, const float* __restrict__ mem_kv,
    const float* __restrict__ vbuf, const float* __restrict__ strat,
    float* __restrict__ att) {
    const int wid = threadIdx.x >> 6, lane = threadIdx.x & 63;
    const int s = blockIdx.x * 4 + wid, h = blockIdx.y;
    __shared__ __align__(16) float qs_a[4][64];
    __shared__ __align__(16) float rqs_a[4][64];
    __shared__ float paw_a[4][192];
    float* qs  = qs_a[wid];
    float* rqs = rqs_a[wid];
    float* paw = paw_a[wid];
    qs[lane]  = qkv[s * 1536 + h * 64 + lane];
    rqs[lane] = rq[s * 512 + h * 64 + lane];
    // no barrier: wave-local LDS dependency

    // ---- compressed attention QK (key = lane, 36 keys) ----
    bool cvalid = (lane < NMEM) || (lane < 36 && (lane - NMEM + 1) * CB - 1 < s);
    int jc = (lane < 36) ? lane : 35;
    const float* ckrow = (jc < NMEM) ? (mem_kv + (h * 4 + jc) * 64)
                                     : (ckc + (size_t)(h * 32 + jc - NMEM) * 64);
    float simc = dot64i(qs, ckrow) * SCALE;
    simc = cvalid ? simc : -FLT_MAX;
    float mx = redmax64(simc);
    float e = (simc == -FLT_MAX) ? 0.0f : expf(simc - mx);
    float tot = redsum64(e);
    float ca = e / tot;
    paw[lane] = (lane < 36) ? ca : 0.0f;

    // ---- comp PV (uniform rows via LDS weights; lane = d) ----
    float cacc;
    {
        const float* mv = mem_kv + 2048 + h * 256 + lane;
        float c0 = paw[0] * mv[0];
        float c1 = paw[1] * mv[64];
        float c2 = paw[2] * mv[128];
        float c3 = paw[3] * mv[192];
        const float* cvb = cvc + h * 2048 + lane;
#pragma unroll
        for (int j = 0; j < 32; j += 4) {
            c0 += paw[4 + j] * cvb[(j + 0) * 64];
            c1 += paw[5 + j] * cvb[(j + 1) * 64];
            c2 += paw[6 + j] * cvb[(j + 2) * 64];
            c3 += paw[7 + j] * cvb[(j + 3) * 64];
        }
        cacc = (c0 + c1) + (c2 + c3);
    }

    // ---- top-4 (wave-parallel, lowest-index tie-break) ----
    float tval = (lane >= NMEM && lane < 36) ? ca : -1.0f;
    int tidx = lane - NMEM;
    int sel0, sel1, sel2, sel3, msk = 0;
#pragma unroll
    for (int t = 0; t < NSEL; ++t) {
        float bv = tval; int bi = tidx;
        for (int o = 32; o > 0; o >>= 1) {
            float ov = __shfl_xor(bv, o);
            int oi = __shfl_xor(bi, o);
            if (ov > bv || (ov == bv && oi < bi)) { bv = ov; bi = oi; }
        }
        if (t == 0) sel0 = bi; else if (t == 1) sel1 = bi;
        else if (t == 2) sel2 = bi; else sel3 = bi;
        if (bv > 1e-10f) msk |= 1 << t;
        if (tidx == bi && lane >= NMEM && lane < 36) tval = -1.0f;
    }

    // ---- fine QK (per-lane rows, row-major rk) ----
    const int t31 = lane & 31;
    const bool hiw = lane >= 32;
    const int own = s >> 5, p = s & 31;
    const float* rkh = rk + h * 64;
    int rowA = (hiw ? sel1 : sel0) * 32 + t31;
    int rowB = (hiw ? sel3 : sel2) * 32 + t31;
    int rowC = own * 32 + t31;
    float simA = dot64i(rqs, rkh + (size_t)rowA * 512) * SCALE;
    float simB = dot64i(rqs, rkh + (size_t)rowB * 512) * SCALE;
    float simC = dot64i(rqs, rkh + (size_t)rowC * 512) * SCALE;
    bool valA = hiw ? ((msk >> 1) & 1) : (msk & 1);
    bool valB = hiw ? ((msk >> 3) & 1) : ((msk >> 2) & 1);
    bool valC = (!hiw) && (t31 <= p);
    simA = valA ? simA : -FLT_MAX;
    simB = valB ? simB : -FLT_MAX;
    simC = valC ? simC : -FLT_MAX;

    float fmx = redmax64(fmaxf(fmaxf(simA, simB), simC));
    float eA = (simA == -FLT_MAX) ? 0.0f : expf(simA - fmx);
    float eB = (simB == -FLT_MAX) ? 0.0f : expf(simB - fmx);
    float eC = (simC == -FLT_MAX) ? 0.0f : expf(simC - fmx);
    float finv = 1.0f / redsum64(eA + eB + eC);
    paw[lane] = eA * finv;         // slots 0 (lanes 0-31), 1 (lanes 32-63)
    paw[64 + lane] = eB * finv;    // slots 2, 3
    paw[128 + lane] = eC * finv;   // own block (lanes 0-31; 160..191 unused)

    // ---- fine PV (uniform rows from sel*, weights from wave-local LDS; lane = d) ----
    const float* vh = vbuf + (size_t)h * 65536 + lane;
    float facc;
    {
        float f0 = 0, f1 = 0, f2 = 0, f3 = 0, f4 = 0;
        if (msk & 1) { const float* vb0 = vh + (size_t)sel0 * 2048;
#pragma unroll
            for (int kk = 0; kk < 32; ++kk) f0 += paw[kk] * vb0[kk * 64]; }
        if (msk & 2) { const float* vb1 = vh + (size_t)sel1 * 2048;
#pragma unroll
            for (int kk = 0; kk < 32; ++kk) f1 += paw[32 + kk] * vb1[kk * 64]; }
        if (msk & 4) { const float* vb2 = vh + (size_t)sel2 * 2048;
#pragma unroll
            for (int kk = 0; kk < 32; ++kk) f2 += paw[64 + kk] * vb2[kk * 64]; }
        if (msk & 8) { const float* vb3 = vh + (size_t)sel3 * 2048;
#pragma unroll
            for (int kk = 0; kk < 32; ++kk) f3 += paw[96 + kk] * vb3[kk * 64]; }
        { const float* vbo = vh + (size_t)own * 2048;
#pragma unroll
            for (int kk = 0; kk < 32; ++kk) f4 += paw[128 + kk] * vbo[kk * 64]; }
        facc = ((f0 + f1) + (f2 + f3)) + f4;
    }

    // ---- sliding window: 64 lane-keys + uniform 65th key ----
    const int lo = (s > WIN) ? s - WIN : 0;
    const int cnt = s - lo + 1;          // <= 65
    float sA = dot64i(rqs, rkh + (size_t)(lo + lane) * 512) * SCALE;  // rows <= 1022
    sA = (lane < cnt) ? sA : -FLT_MAX;
    bool v65 = (s >= 64);
    float s65 = dot64i(rqs, rkh + (size_t)(lo + 64) * 512) * SCALE;   // uniform row (broadcast loads)
    float smx = redmax64(fmaxf(sA, v65 ? s65 : -FLT_MAX));
    float esA = (sA == -FLT_MAX) ? 0.0f : expf(sA - smx);
    float es65 = v65 ? expf(s65 - smx) : 0.0f;
    float ssum = redsum64(esA) + es65;
    float sinv = 1.0f / ssum;
    paw[lane] = esA * sinv;
    float sacc;
    {
        float s0 = 0, s1 = 0, s2 = 0, s3 = 0;
        const float* vlo = vh + (size_t)lo * 64;
#pragma unroll
        for (int kk = 0; kk < 64; kk += 4) {
            s0 += paw[kk]     * vlo[(kk + 0) * 64];
            s1 += paw[kk + 1] * vlo[(kk + 1) * 64];
            s2 += paw[kk + 2] * vlo[(kk + 2) * 64];
            s3 += paw[kk + 3] * vlo[(kk + 3) * 64];
        }
        sacc = (s0 + s1) + (s2 + s3);
        if (v65) sacc += (es65 * sinv) * vlo[64 * 64];
    }

    // ---- gated combine ----
    const float* st = strat + s * 24 + h * 3;
    att[s * 512 + h * 64 + lane] = st[0] * cacc + st[1] * facc + st[2] * sacc;
}

extern "C" void kernel_launch(void* const* d_in, const int* in_sizes, int n_in,
                              void* d_out, int out_size, void* d_ws, size_t ws_size,
                              hipStream_t stream) {
    const float* inp     = (const float*)d_in[0];
    const float* norm_g  = (const float*)d_in[1];
    const float* w_qkv   = (const float*)d_in[2];
    const float* k_pos   = (const float*)d_in[3];
    const float* v_pos   = (const float*)d_in[4];
    const float* kc_w1   = (const float*)d_in[5];
    const float* kc_b1   = (const float*)d_in[6];
    const float* kc_w2   = (const float*)d_in[7];
    const float* kc_b2   = (const float*)d_in[8];
    const float* vc_w1   = (const float*)d_in[9];
    const float* vc_b1   = (const float*)d_in[10];
    const float* vc_w2   = (const float*)d_in[11];
    const float* vc_b2   = (const float*)d_in[12];
    const float* mem_kv  = (const float*)d_in[13];
    const float* strat_w = (const float*)d_in[14];
    const float* strat_b = (const float*)d_in[15];
    const float* out_w   = (const float*)d_in[16];
    float* out = (float*)d_out;

    float* ws = (float*)d_ws;
    float* x     = ws + OFF_X;
    float* qkv   = ws + OFF_QKV;
    float* rq    = ws + OFF_RQ;
    float* rk    = ws + OFF_RK;
    float* vbuf  = ws + OFF_VBUF;
    float* ckc   = ws + OFF_CKC;
    float* cvc   = ws + OFF_CVC;
    float* strat = ws + OFF_STRAT;
    float* att   = ws + OFF_ATT;
    float* hkv   = ws + OFF_HK;
    float* qkvp  = ws + OFF_QKVP;
    float* compp = ws + OFF_COMPP;
    float* outp  = ws + OFF_OUTP;

    rmsnorm_strat_k<<<1024, 256, 0, stream>>>(inp, norm_g, strat_w, strat_b, x, strat);
    gemm_sk_k<<<dim3(16, 24, 2), 256, 0, stream>>>(x, w_qkv, qkvp, 1024, 1536, 512, 2);
    reduce_qkv_k<<<1536, 256, 0, stream>>>(qkvp, qkv, vbuf);
    rope_apply_k<<<1024, 256, 0, stream>>>(qkv, rq, rk);
    gemm_comp_k<<<dim3(4, 32, 8), 256, 0, stream>>>(qkv, k_pos, v_pos, kc_w1, vc_w1, compp);
    reduce_comp_k<<<1024, 256, 0, stream>>>(compp, kc_b1, vc_b1, hkv);
    gemm_skinny_z2_k<<<dim3(256, 1, 2), 256, 0, stream>>>(hkv, kc_w2, kc_b2, vc_w2, vc_b2, ckc, cvc);
    attn_fused_k<<<dim3(256, 8), 256, 0, stream>>>(qkv, rq, rk, ckc, cvc, mem_kv, vbuf, strat, att);
    gemm_sk_k<<<dim3(16, 8, 4), 256, 0, stream>>>(att, out_w, outp, 1024, 512, 512, 4);
    reduce_k<4><<<512, 256, 0, stream>>>(outp, out, 1024 * 512);
}